// Round 2
// baseline (801.499 us; speedup 1.0000x reference)
//
#include <hip/hip_runtime.h>
#include <hip/hip_bf16.h>
#include <math.h>

typedef __bf16 bf16;
typedef __bf16 bf16x8 __attribute__((ext_vector_type(8)));
typedef float f32x4 __attribute__((ext_vector_type(4)));

#define GLB __attribute__((address_space(1)))
#define LDSAS __attribute__((address_space(3)))

// ---------------------------------------------------------------------------
// Dtype probe: flag=1 if d_in[0] is genuine fp32, 0 if packed bf16.
// Bits 14:7 of a u32 word = mantissa bits (uniform) for fp32, but = the low
// bf16's exponent field (clustered near 127 for N(0,1) data) if packed bf16.
// ---------------------------------------------------------------------------
__global__ void probe_dtype(const unsigned int* __restrict__ X, int* __restrict__ flag) {
  int t = threadIdx.x;
  int cnt = 0;
  for (int i = t; i < 512; i += 64) {
    unsigned int e = (X[i] >> 7) & 0xFF;
    cnt += (e >= 110 && e <= 135) ? 1 : 0;
  }
#pragma unroll
  for (int off = 32; off > 0; off >>= 1) cnt += __shfl_down(cnt, off, 64);
  if (t == 0) flag[0] = (cnt < 256) ? 1 : 0;  // few in-range -> fp32
}

// ---------------------------------------------------------------------------
// Cast X -> bf16 (dual-read per flag). 4 elements/thread.
// ---------------------------------------------------------------------------
__global__ void cast_to_bf16(const void* __restrict__ X, bf16* __restrict__ Y,
                             const int* __restrict__ flag, int n) {
  const int i = (blockIdx.x * 256 + threadIdx.x) * 4;
  if (i >= n) return;
  if (flag[0]) {
    const float* xf = (const float*)X;
#pragma unroll
    for (int j = 0; j < 4; ++j) Y[i + j] = (bf16)xf[i + j];
  } else {
    const bf16* xb = (const bf16*)X;
#pragma unroll
    for (int j = 0; j < 4; ++j) Y[i + j] = xb[i + j];
  }
}

// ---------------------------------------------------------------------------
// Transpose+cast: W[K][N] (fp32 or bf16) -> Wt[N][K] bf16. 32x32 LDS tiles.
// ---------------------------------------------------------------------------
__global__ void transpose_to_bf16(const void* __restrict__ W, bf16* __restrict__ Wt,
                                  const int* __restrict__ flag, int K, int N) {
  __shared__ bf16 tile[32][34];
  const int n0 = blockIdx.x * 32, k0 = blockIdx.y * 32;
  const int tx = threadIdx.x, ty = threadIdx.y;
  const int f = flag[0];
#pragma unroll
  for (int j = 0; j < 4; ++j) {
    const size_t idx = (size_t)(k0 + ty + j * 8) * N + n0 + tx;
    tile[ty + j * 8][tx] = f ? (bf16)((const float*)W)[idx] : ((const bf16*)W)[idx];
  }
  __syncthreads();
#pragma unroll
  for (int j = 0; j < 4; ++j)
    Wt[(size_t)(n0 + ty + j * 8) * K + k0 + tx] = tile[tx][ty + j * 8];
}

// ---------------------------------------------------------------------------
// m97-style bf16 GEMM: C = A[M][K] * Bt[N][K]^T, fp32 accum.
// Output bf16, or fp32 when (flagp && flagp[0]).
// ---------------------------------------------------------------------------
__global__ __launch_bounds__(256, 2) void gemm_bt(
    const bf16* __restrict__ A, const bf16* __restrict__ Bt,
    void* __restrict__ C, const int* __restrict__ flagp, int M, int N, int K) {
  __shared__ bf16 As[128 * 32];
  __shared__ bf16 Bs[128 * 32];
  const int t = threadIdx.x;
  const int m0 = blockIdx.y * 128, n0 = blockIdx.x * 128;
  const int lane = t & 63, n16 = lane & 15, quad = lane >> 4;
  const int w = t >> 6, wrow = w >> 1, wcol = w & 1;

  f32x4 acc[4][4] = {};
  const int colA = (t & 3) * 8;
  const int rA = t >> 2;

  for (int k0 = 0; k0 < K; k0 += 32) {
#pragma unroll
    for (int i = 0; i < 2; ++i) {
      const int elem = i * 2048 + t * 8;
      const int row = i * 64 + rA;
      __builtin_amdgcn_global_load_lds(
          (const GLB void*)(A + (size_t)(m0 + row) * K + k0 + colA),
          (LDSAS void*)(&As[elem]), 16, 0, 0);
      __builtin_amdgcn_global_load_lds(
          (const GLB void*)(Bt + (size_t)(n0 + row) * K + k0 + colA),
          (LDSAS void*)(&Bs[elem]), 16, 0, 0);
    }
    __syncthreads();
    bf16x8 af[4], bfr[4];
#pragma unroll
    for (int i = 0; i < 4; ++i) {
      af[i] = *(const bf16x8*)&As[(wrow * 64 + i * 16 + n16) * 32 + quad * 8];
      bfr[i] = *(const bf16x8*)&Bs[(wcol * 64 + i * 16 + n16) * 32 + quad * 8];
    }
#pragma unroll
    for (int mi = 0; mi < 4; ++mi)
#pragma unroll
      for (int ni = 0; ni < 4; ++ni)
        acc[mi][ni] = __builtin_amdgcn_mfma_f32_16x16x32_bf16(
            af[mi], bfr[ni], acc[mi][ni], 0, 0, 0);
    __syncthreads();
  }
  const bool f32out = (flagp != nullptr) && (flagp[0] != 0);
  // C/D layout: col=lane&15, row=quad*4+reg
  if (f32out) {
    float* Cf = (float*)C;
#pragma unroll
    for (int mi = 0; mi < 4; ++mi)
#pragma unroll
      for (int ni = 0; ni < 4; ++ni) {
        const int r0 = m0 + wrow * 64 + mi * 16 + quad * 4;
        const int c = n0 + wcol * 64 + ni * 16 + n16;
#pragma unroll
        for (int r = 0; r < 4; ++r) Cf[(size_t)(r0 + r) * N + c] = acc[mi][ni][r];
      }
  } else {
    bf16* Cb = (bf16*)C;
#pragma unroll
    for (int mi = 0; mi < 4; ++mi)
#pragma unroll
      for (int ni = 0; ni < 4; ++ni) {
        const int r0 = m0 + wrow * 64 + mi * 16 + quad * 4;
        const int c = n0 + wcol * 64 + ni * 16 + n16;
#pragma unroll
        for (int r = 0; r < 4; ++r) Cb[(size_t)(r0 + r) * N + c] = (bf16)acc[mi][ni][r];
      }
  }
}

// ---------------------------------------------------------------------------
// RoPE in-place on bf16 [S][heads*128]; pairs (d, d+64).
// ---------------------------------------------------------------------------
__global__ void rope_kernel(bf16* __restrict__ X, const int* __restrict__ pos,
                            int heads) {
  const int idx = blockIdx.x * 256 + threadIdx.x;
  const int i = idx & 63;
  const int hh = (idx >> 6) % heads;
  const int s = idx / (64 * heads);
  const size_t base = (size_t)s * heads * 128 + hh * 128 + i;
  const float x1 = (float)X[base], x2 = (float)X[base + 64];
  const float p = (float)pos[s];
  const float inv = exp2f((float)i * -0.2076205088f);  // 10000^(-i/64)
  float sn, cs;
  sincosf(p * inv, &sn, &cs);
  X[base] = (bf16)(x1 * cs - x2 * sn);
  X[base + 64] = (bf16)(x2 * cs + x1 * sn);
}

// ---------------------------------------------------------------------------
// Causal GQA flash attention (bf16 in/out, fp32 softmax+accum).
// Block=(qt,h): 64 q rows, 4 waves x 16 rows.
// ---------------------------------------------------------------------------
__global__ __launch_bounds__(256) void flash_attn(
    const bf16* __restrict__ Q, const bf16* __restrict__ Kg,
    const bf16* __restrict__ Vg, bf16* __restrict__ O) {
  constexpr int VROW = 72;
  constexpr float NEG = -1e30f;
  __shared__ bf16 Ks[64 * 136];
  __shared__ bf16 Vt[128 * VROW];
  __shared__ bf16 Ps[4 * 16 * VROW];
  const int qt = blockIdx.x, h = blockIdx.y, hkv = h >> 2;
  const int t = threadIdx.x, w = t >> 6, lane = t & 63;
  const int n16 = lane & 15, quad = lane >> 4;

  bf16x8 qa[4];
  {
    const bf16* qp = Q + (size_t)(qt * 64 + w * 16 + n16) * 4096 + h * 128 + quad * 8;
#pragma unroll
    for (int kf = 0; kf < 4; ++kf) qa[kf] = *(const bf16x8*)(qp + kf * 32);
  }
  f32x4 o[8] = {};
  float m_[4] = {NEG, NEG, NEG, NEG};
  float l_[4] = {0.f, 0.f, 0.f, 0.f};

  const int srow = t >> 4;
  const int scol = (t & 15) * 8;
  const int sxor = (t & 7) * 8;

  for (int kt = 0; kt <= qt; ++kt) {
#pragma unroll
    for (int j = 0; j < 4; ++j) {
      const int rr = j * 16 + srow;
      const size_t goff = (size_t)(kt * 64 + rr) * 1024 + hkv * 128 + scol;
      *(bf16x8*)&Ks[rr * 136 + scol] = *(const bf16x8*)(Kg + goff);
      const bf16x8 vv = *(const bf16x8*)(Vg + goff);
      const int wc = rr ^ sxor;
#pragma unroll
      for (int u = 0; u < 8; ++u) Vt[(scol + u) * VROW + wc] = vv[u];
    }
    __syncthreads();

    float p[4][4];
#pragma unroll
    for (int ns = 0; ns < 4; ++ns) {
      f32x4 c = {};
#pragma unroll
      for (int kf = 0; kf < 4; ++kf)
        c = __builtin_amdgcn_mfma_f32_16x16x32_bf16(
            qa[kf], *(const bf16x8*)&Ks[(ns * 16 + n16) * 136 + kf * 32 + quad * 8],
            c, 0, 0, 0);
      const int kvi = kt * 64 + ns * 16 + n16;
#pragma unroll
      for (int r = 0; r < 4; ++r) {
        const int qi = qt * 64 + w * 16 + quad * 4 + r;
        p[ns][r] = (kvi > qi) ? NEG : c[r] * 0.08838834764831845f;
      }
    }
    float alpha[4];
#pragma unroll
    for (int r = 0; r < 4; ++r) {
      float rmax = fmaxf(fmaxf(p[0][r], p[1][r]), fmaxf(p[2][r], p[3][r]));
#pragma unroll
      for (int off = 1; off < 16; off <<= 1)
        rmax = fmaxf(rmax, __shfl_xor(rmax, off, 64));
      const float mn = fmaxf(m_[r], rmax);
      alpha[r] = __expf(m_[r] - mn);
      float rs = 0.f;
#pragma unroll
      for (int ns = 0; ns < 4; ++ns) {
        const float e = __expf(p[ns][r] - mn);
        p[ns][r] = e;
        rs += e;
      }
#pragma unroll
      for (int off = 1; off < 16; off <<= 1) rs += __shfl_xor(rs, off, 64);
      l_[r] = l_[r] * alpha[r] + rs;
      m_[r] = mn;
    }
#pragma unroll
    for (int dt = 0; dt < 8; ++dt)
#pragma unroll
      for (int r = 0; r < 4; ++r) o[dt][r] *= alpha[r];
#pragma unroll
    for (int ns = 0; ns < 4; ++ns)
#pragma unroll
      for (int r = 0; r < 4; ++r)
        Ps[(w * 16 + quad * 4 + r) * VROW + ns * 16 + n16] = (bf16)p[ns][r];
    __syncthreads();
    bf16x8 a0 = *(const bf16x8*)&Ps[(w * 16 + n16) * VROW + quad * 8];
    bf16x8 a1 = *(const bf16x8*)&Ps[(w * 16 + n16) * VROW + 32 + quad * 8];
#pragma unroll
    for (int dt = 0; dt < 8; ++dt) {
      const int d = dt * 16 + n16;
      const int g8 = ((d >> 3) & 7) * 8;
      const bf16x8 b0 = *(const bf16x8*)&Vt[d * VROW + ((quad * 8) ^ g8)];
      o[dt] = __builtin_amdgcn_mfma_f32_16x16x32_bf16(a0, b0, o[dt], 0, 0, 0);
      const bf16x8 b1 = *(const bf16x8*)&Vt[d * VROW + ((32 + quad * 8) ^ g8)];
      o[dt] = __builtin_amdgcn_mfma_f32_16x16x32_bf16(a1, b1, o[dt], 0, 0, 0);
    }
    __syncthreads();
  }
#pragma unroll
  for (int dt = 0; dt < 8; ++dt)
#pragma unroll
    for (int r = 0; r < 4; ++r) {
      const int qi = qt * 64 + w * 16 + quad * 4 + r;
      O[(size_t)qi * 4096 + h * 128 + dt * 16 + n16] = (bf16)(o[dt][r] / l_[r]);
    }
}

// ---------------------------------------------------------------------------
extern "C" void kernel_launch(void* const* d_in, const int* in_sizes, int n_in,
                              void* d_out, int out_size, void* d_ws, size_t ws_size,
                              hipStream_t stream) {
  (void)in_sizes; (void)n_in; (void)out_size; (void)ws_size;
  const void* X = d_in[0];                 // [2048][4096] fp32 or bf16
  const int* pos = (const int*)d_in[1];    // [2048]
  const void* Wq = d_in[2];                // [4096][4096]
  const void* Wk = d_in[3];                // [4096][1024]
  const void* Wv = d_in[4];                // [4096][1024]
  const void* Wo = d_in[5];                // [4096][4096]

  char* ws = (char*)d_ws;
  const size_t MB = 1ull << 20;
  int* flag = (int*)(ws + 0);
  bf16* Xb  = (bf16*)(ws + 1 * MB);    // 16 MiB
  bf16* Wqt = (bf16*)(ws + 17 * MB);   // 32 MiB
  bf16* Wkt = (bf16*)(ws + 49 * MB);   // 8 MiB
  bf16* Wvt = (bf16*)(ws + 57 * MB);   // 8 MiB
  bf16* Wot = (bf16*)(ws + 65 * MB);   // 32 MiB
  bf16* Qb  = (bf16*)(ws + 97 * MB);   // 16 MiB
  bf16* Kb  = (bf16*)(ws + 113 * MB);  // 4 MiB
  bf16* Vb  = (bf16*)(ws + 117 * MB);  // 4 MiB
  bf16* attn= (bf16*)(ws + 121 * MB);  // 16 MiB -> 137 MiB total

  probe_dtype<<<1, 64, 0, stream>>>((const unsigned int*)X, flag);

  cast_to_bf16<<<8192, 256, 0, stream>>>(X, Xb, flag, 2048 * 4096);

  const dim3 tb(32, 8);
  transpose_to_bf16<<<dim3(128, 128), tb, 0, stream>>>(Wq, Wqt, flag, 4096, 4096);
  transpose_to_bf16<<<dim3(32, 128), tb, 0, stream>>>(Wk, Wkt, flag, 4096, 1024);
  transpose_to_bf16<<<dim3(32, 128), tb, 0, stream>>>(Wv, Wvt, flag, 4096, 1024);
  transpose_to_bf16<<<dim3(128, 128), tb, 0, stream>>>(Wo, Wot, flag, 4096, 4096);

  gemm_bt<<<dim3(32, 16), 256, 0, stream>>>(Xb, Wqt, Qb, nullptr, 2048, 4096, 4096);
  gemm_bt<<<dim3(8, 16), 256, 0, stream>>>(Xb, Wkt, Kb, nullptr, 2048, 1024, 4096);
  gemm_bt<<<dim3(8, 16), 256, 0, stream>>>(Xb, Wvt, Vb, nullptr, 2048, 1024, 4096);

  rope_kernel<<<(2048 * 32 * 64) / 256, 256, 0, stream>>>(Qb, pos, 32);
  rope_kernel<<<(2048 * 8 * 64) / 256, 256, 0, stream>>>(Kb, pos, 8);

  flash_attn<<<dim3(32, 32), 256, 0, stream>>>(Qb, Kb, Vb, attn);

  gemm_bt<<<dim3(32, 16), 256, 0, stream>>>(attn, Wot, d_out, flag, 2048, 4096, 4096);
}

// Round 3
// 563.331 us; speedup vs baseline: 1.4228x; 1.4228x over previous
//
#include <hip/hip_runtime.h>
#include <hip/hip_bf16.h>
#include <math.h>

typedef __bf16 bf16;
typedef __bf16 bf16x8 __attribute__((ext_vector_type(8)));
typedef float f32x4 __attribute__((ext_vector_type(4)));

#define GLB __attribute__((address_space(1)))
#define LDSAS __attribute__((address_space(3)))

// ---------------------------------------------------------------------------
// Dtype probe: flag=1 if d_in[0] is genuine fp32, 0 if packed bf16.
// ---------------------------------------------------------------------------
__global__ void probe_dtype(const unsigned int* __restrict__ X, int* __restrict__ flag) {
  int t = threadIdx.x;
  int cnt = 0;
  for (int i = t; i < 512; i += 64) {
    unsigned int e = (X[i] >> 7) & 0xFF;
    cnt += (e >= 110 && e <= 135) ? 1 : 0;
  }
#pragma unroll
  for (int off = 32; off > 0; off >>= 1) cnt += __shfl_down(cnt, off, 64);
  if (t == 0) flag[0] = (cnt < 256) ? 1 : 0;
}

// ---------------------------------------------------------------------------
// Cast X -> bf16 (dual-read per flag). 4 elements/thread.
// ---------------------------------------------------------------------------
__global__ void cast_to_bf16(const void* __restrict__ X, bf16* __restrict__ Y,
                             const int* __restrict__ flag, int n) {
  const int i = (blockIdx.x * 256 + threadIdx.x) * 4;
  if (i >= n) return;
  if (flag[0]) {
    const float* xf = (const float*)X;
#pragma unroll
    for (int j = 0; j < 4; ++j) Y[i + j] = (bf16)xf[i + j];
  } else {
    const bf16* xb = (const bf16*)X;
#pragma unroll
    for (int j = 0; j < 4; ++j) Y[i + j] = xb[i + j];
  }
}

// ---------------------------------------------------------------------------
// Weight transpose+cast: W[K][N] (fp32/bf16 per flag) -> Wt[N][K] bf16.
// ---------------------------------------------------------------------------
__global__ void transpose_to_bf16(const void* __restrict__ W, bf16* __restrict__ Wt,
                                  const int* __restrict__ flag, int K, int N) {
  __shared__ bf16 tile[32][34];
  const int n0 = blockIdx.x * 32, k0 = blockIdx.y * 32;
  const int tx = threadIdx.x, ty = threadIdx.y;
  const int f = flag[0];
#pragma unroll
  for (int j = 0; j < 4; ++j) {
    const size_t idx = (size_t)(k0 + ty + j * 8) * N + n0 + tx;
    tile[ty + j * 8][tx] = f ? (bf16)((const float*)W)[idx] : ((const bf16*)W)[idx];
  }
  __syncthreads();
#pragma unroll
  for (int j = 0; j < 4; ++j)
    Wt[(size_t)(n0 + ty + j * 8) * K + k0 + tx] = tile[tx][ty + j * 8];
}

// ---------------------------------------------------------------------------
// V extract+transpose: V view [2048 s][1024 v] (row stride 6144, bf16)
// -> Vt[1024 v][2048 s] bf16.
// ---------------------------------------------------------------------------
__global__ void transpose_v(const bf16* __restrict__ V, bf16* __restrict__ Vt) {
  __shared__ bf16 tile[32][34];
  const int v0 = blockIdx.x * 32, s0 = blockIdx.y * 32;
  const int tx = threadIdx.x, ty = threadIdx.y;
#pragma unroll
  for (int j = 0; j < 4; ++j)
    tile[ty + j * 8][tx] = V[(size_t)(s0 + ty + j * 8) * 6144 + v0 + tx];
  __syncthreads();
  // tile[s_local][v_local]; write Vt[v][s]
#pragma unroll
  for (int j = 0; j < 4; ++j)
    Vt[(size_t)(v0 + ty + j * 8) * 2048 + s0 + tx] = tile[tx][ty + j * 8];
}

// ---------------------------------------------------------------------------
// m97-style bf16 GEMM: C = A[M][K] * Bt[N][K]^T, fp32 accum.
// Output bf16, or fp32 when (flagp && flagp[0]).
// ---------------------------------------------------------------------------
__global__ __launch_bounds__(256, 2) void gemm_bt(
    const bf16* __restrict__ A, const bf16* __restrict__ Bt,
    void* __restrict__ C, const int* __restrict__ flagp, int M, int N, int K) {
  __shared__ bf16 As[128 * 32];
  __shared__ bf16 Bs[128 * 32];
  const int t = threadIdx.x;
  const int m0 = blockIdx.y * 128, n0 = blockIdx.x * 128;
  const int lane = t & 63, n16 = lane & 15, quad = lane >> 4;
  const int w = t >> 6, wrow = w >> 1, wcol = w & 1;

  f32x4 acc[4][4] = {};
  const int colA = (t & 3) * 8;
  const int rA = t >> 2;

  for (int k0 = 0; k0 < K; k0 += 32) {
#pragma unroll
    for (int i = 0; i < 2; ++i) {
      const int elem = i * 2048 + t * 8;
      const int row = i * 64 + rA;
      __builtin_amdgcn_global_load_lds(
          (const GLB void*)(A + (size_t)(m0 + row) * K + k0 + colA),
          (LDSAS void*)(&As[elem]), 16, 0, 0);
      __builtin_amdgcn_global_load_lds(
          (const GLB void*)(Bt + (size_t)(n0 + row) * K + k0 + colA),
          (LDSAS void*)(&Bs[elem]), 16, 0, 0);
    }
    __syncthreads();
    bf16x8 af[4], bfr[4];
#pragma unroll
    for (int i = 0; i < 4; ++i) {
      af[i] = *(const bf16x8*)&As[(wrow * 64 + i * 16 + n16) * 32 + quad * 8];
      bfr[i] = *(const bf16x8*)&Bs[(wcol * 64 + i * 16 + n16) * 32 + quad * 8];
    }
#pragma unroll
    for (int mi = 0; mi < 4; ++mi)
#pragma unroll
      for (int ni = 0; ni < 4; ++ni)
        acc[mi][ni] = __builtin_amdgcn_mfma_f32_16x16x32_bf16(
            af[mi], bfr[ni], acc[mi][ni], 0, 0, 0);
    __syncthreads();
  }
  const bool f32out = (flagp != nullptr) && (flagp[0] != 0);
  if (f32out) {
    float* Cf = (float*)C;
#pragma unroll
    for (int mi = 0; mi < 4; ++mi)
#pragma unroll
      for (int ni = 0; ni < 4; ++ni) {
        const int r0 = m0 + wrow * 64 + mi * 16 + quad * 4;
        const int c = n0 + wcol * 64 + ni * 16 + n16;
#pragma unroll
        for (int r = 0; r < 4; ++r) Cf[(size_t)(r0 + r) * N + c] = acc[mi][ni][r];
      }
  } else {
    bf16* Cb = (bf16*)C;
#pragma unroll
    for (int mi = 0; mi < 4; ++mi)
#pragma unroll
      for (int ni = 0; ni < 4; ++ni) {
        const int r0 = m0 + wrow * 64 + mi * 16 + quad * 4;
        const int c = n0 + wcol * 64 + ni * 16 + n16;
#pragma unroll
        for (int r = 0; r < 4; ++r) Cb[(size_t)(r0 + r) * N + c] = (bf16)acc[mi][ni][r];
      }
  }
}

// ---------------------------------------------------------------------------
// RoPE in-place on strided bf16 view: row s at X + s*stride + col0, heads*128.
// ---------------------------------------------------------------------------
__global__ void rope_kernel(bf16* __restrict__ X, const int* __restrict__ pos,
                            int heads, int stride, int col0) {
  const int idx = blockIdx.x * 256 + threadIdx.x;
  const int i = idx & 63;
  const int hh = (idx >> 6) % heads;
  const int s = idx / (64 * heads);
  bf16* px = X + (size_t)s * stride + col0 + hh * 128 + i;
  const float x1 = (float)px[0], x2 = (float)px[64];
  const float p = (float)pos[s];
  const float inv = exp2f((float)i * -0.2076205088f);  // 10000^(-i/64)
  float sn, cs;
  sincosf(p * inv, &sn, &cs);
  px[0] = (bf16)(x1 * cs - x2 * sn);
  px[64] = (bf16)(x2 * cs + x1 * sn);
}

// ---------------------------------------------------------------------------
// Causal GQA flash attention v2.
// Grid (16 pair, 32 heads). Block p handles q-tiles {p, 31-p} (33 k-tiles).
// K staged row-major padded (136); V^T staged b128 with 16B XOR swizzle:
// element (d,kv) at Vs[d*64 + ((kv>>3 ^ (d&7))*8) + (kv&7)] -> even bank
// spread on both staging writes and fragment reads. Mask only on diagonal.
// ---------------------------------------------------------------------------
__global__ __launch_bounds__(256) void flash_attn(
    const bf16* __restrict__ QKV, const bf16* __restrict__ Vt_g,
    bf16* __restrict__ O) {
  __shared__ bf16 Ks[64 * 136];
  __shared__ bf16 Vs[128 * 64];
  __shared__ bf16 Ps[64 * 72];
  const int pairp = blockIdx.x;
  const int h = blockIdx.y, hkv = h >> 2;
  const int t = threadIdx.x, w = t >> 6, lane = t & 63;
  const int n16 = lane & 15, quad = lane >> 4;
  const bf16* Qp = QKV + h * 128;
  const bf16* Kp = QKV + 4096 + hkv * 128;
  const int srow = t >> 4, scol = (t & 15) * 8;
  const int vc = t & 7;

  for (int pass = 0; pass < 2; ++pass) {
    const int qt = (pass == 0) ? pairp : 31 - pairp;
    bf16x8 qa[4];
    {
      const bf16* qrow = Qp + (size_t)(qt * 64 + w * 16 + n16) * 6144 + quad * 8;
#pragma unroll
      for (int kf = 0; kf < 4; ++kf) qa[kf] = *(const bf16x8*)(qrow + kf * 32);
    }
    f32x4 o[8] = {};
    float m_[4] = {-1e30f, -1e30f, -1e30f, -1e30f};
    float l_[4] = {0.f, 0.f, 0.f, 0.f};

    for (int kt = 0; kt <= qt; ++kt) {
      // ---- stage K rows (vector b128, padded rows)
#pragma unroll
      for (int j = 0; j < 4; ++j) {
        const int rr = j * 16 + srow;
        *(bf16x8*)&Ks[rr * 136 + scol] =
            *(const bf16x8*)(Kp + (size_t)(kt * 64 + rr) * 6144 + scol);
      }
      // ---- stage V^T swizzled (vector b128)
#pragma unroll
      for (int it = 0; it < 4; ++it) {
        const int d = it * 32 + (t >> 3);
        const bf16x8 vv = *(const bf16x8*)(
            Vt_g + (size_t)(hkv * 128 + d) * 2048 + kt * 64 + vc * 8);
        *(bf16x8*)&Vs[d * 64 + ((vc ^ (d & 7)) * 8)] = vv;
      }
      __syncthreads();

      // ---- S = Q K^T / sqrt(D); mask only on diagonal tile
      float p[4][4];
      const bool diag = (kt == qt);
#pragma unroll
      for (int ns = 0; ns < 4; ++ns) {
        f32x4 c = {};
#pragma unroll
        for (int kf = 0; kf < 4; ++kf)
          c = __builtin_amdgcn_mfma_f32_16x16x32_bf16(
              qa[kf],
              *(const bf16x8*)&Ks[(ns * 16 + n16) * 136 + kf * 32 + quad * 8],
              c, 0, 0, 0);
        if (diag) {
          const int kvi = ns * 16 + n16;
          const int ql = w * 16 + quad * 4;
#pragma unroll
          for (int r = 0; r < 4; ++r)
            p[ns][r] = (kvi > ql + r) ? -1e30f : c[r] * 0.08838834764831845f;
        } else {
#pragma unroll
          for (int r = 0; r < 4; ++r) p[ns][r] = c[r] * 0.08838834764831845f;
        }
      }
      // ---- online softmax (rows across the 16 lanes of each quad)
      float alpha[4];
#pragma unroll
      for (int r = 0; r < 4; ++r) {
        float rmax = fmaxf(fmaxf(p[0][r], p[1][r]), fmaxf(p[2][r], p[3][r]));
#pragma unroll
        for (int off = 1; off < 16; off <<= 1)
          rmax = fmaxf(rmax, __shfl_xor(rmax, off, 64));
        const float mn = fmaxf(m_[r], rmax);
        alpha[r] = __expf(m_[r] - mn);
        float rs = 0.f;
#pragma unroll
        for (int ns = 0; ns < 4; ++ns) {
          const float e = __expf(p[ns][r] - mn);
          p[ns][r] = e;
          rs += e;
        }
#pragma unroll
        for (int off = 1; off < 16; off <<= 1) rs += __shfl_xor(rs, off, 64);
        l_[r] = l_[r] * alpha[r] + rs;
        m_[r] = mn;
      }
#pragma unroll
      for (int dt = 0; dt < 8; ++dt)
#pragma unroll
        for (int r = 0; r < 4; ++r) o[dt][r] *= alpha[r];
      // ---- P: C-layout -> LDS rows (wave-private region)
#pragma unroll
      for (int ns = 0; ns < 4; ++ns)
#pragma unroll
        for (int r = 0; r < 4; ++r)
          Ps[(w * 16 + quad * 4 + r) * 72 + ns * 16 + n16] = (bf16)p[ns][r];
      __syncthreads();
      // ---- O += P V
      const bf16x8 a0 = *(const bf16x8*)&Ps[(w * 16 + n16) * 72 + quad * 8];
      const bf16x8 a1 = *(const bf16x8*)&Ps[(w * 16 + n16) * 72 + 32 + quad * 8];
#pragma unroll
      for (int dt = 0; dt < 8; ++dt) {
        const int d = dt * 16 + n16;
        const int s7 = d & 7;
        const bf16x8 b0 = *(const bf16x8*)&Vs[d * 64 + ((quad ^ s7) * 8)];
        o[dt] = __builtin_amdgcn_mfma_f32_16x16x32_bf16(a0, b0, o[dt], 0, 0, 0);
        const bf16x8 b1 = *(const bf16x8*)&Vs[d * 64 + (((4 + quad) ^ s7) * 8)];
        o[dt] = __builtin_amdgcn_mfma_f32_16x16x32_bf16(a1, b1, o[dt], 0, 0, 0);
      }
      __syncthreads();
    }
    // ---- epilogue
    float linv[4];
#pragma unroll
    for (int r = 0; r < 4; ++r) linv[r] = 1.f / l_[r];
#pragma unroll
    for (int dt = 0; dt < 8; ++dt)
#pragma unroll
      for (int r = 0; r < 4; ++r) {
        const int qi = qt * 64 + w * 16 + quad * 4 + r;
        O[(size_t)qi * 4096 + h * 128 + dt * 16 + n16] = (bf16)(o[dt][r] * linv[r]);
      }
  }
}

// ---------------------------------------------------------------------------
extern "C" void kernel_launch(void* const* d_in, const int* in_sizes, int n_in,
                              void* d_out, int out_size, void* d_ws, size_t ws_size,
                              hipStream_t stream) {
  (void)in_sizes; (void)n_in; (void)out_size; (void)ws_size;
  const void* X = d_in[0];
  const int* pos = (const int*)d_in[1];
  const void* Wq = d_in[2];
  const void* Wk = d_in[3];
  const void* Wv = d_in[4];
  const void* Wo = d_in[5];

  char* ws = (char*)d_ws;
  const size_t MB = 1ull << 20;
  int* flag   = (int*)(ws + 0);
  bf16* Xb    = (bf16*)(ws + 1 * MB);    // 16 MiB (aliased by attn later)
  bf16* attn  = (bf16*)(ws + 1 * MB);    // alias: Xb dead after QKV GEMM
  bf16* Wqkvt = (bf16*)(ws + 17 * MB);   // [6144][4096] = 48 MiB
  bf16* Wot   = (bf16*)(ws + 65 * MB);   // 32 MiB
  bf16* QKV   = (bf16*)(ws + 97 * MB);   // [2048][6144] = 24 MiB
  bf16* Vt_g  = (bf16*)(ws + 121 * MB);  // [1024][2048] = 4 MiB -> 125 MiB

  probe_dtype<<<1, 64, 0, stream>>>((const unsigned int*)X, flag);
  cast_to_bf16<<<8192, 256, 0, stream>>>(X, Xb, flag, 2048 * 4096);

  const dim3 tb(32, 8);
  transpose_to_bf16<<<dim3(128, 128), tb, 0, stream>>>(Wq, Wqkvt, flag, 4096, 4096);
  transpose_to_bf16<<<dim3(32, 128), tb, 0, stream>>>(Wk, Wqkvt + (size_t)4096 * 4096, flag, 4096, 1024);
  transpose_to_bf16<<<dim3(32, 128), tb, 0, stream>>>(Wv, Wqkvt + (size_t)5120 * 4096, flag, 4096, 1024);
  transpose_to_bf16<<<dim3(128, 128), tb, 0, stream>>>(Wo, Wot, flag, 4096, 4096);

  // fused QKV projection: [2048][4096] @ [4096][6144] -> [2048][6144]
  gemm_bt<<<dim3(48, 16), 256, 0, stream>>>(Xb, Wqkvt, QKV, nullptr, 2048, 6144, 4096);

  rope_kernel<<<16384, 256, 0, stream>>>(QKV, pos, 32, 6144, 0);     // Q
  rope_kernel<<<4096, 256, 0, stream>>>(QKV, pos, 8, 6144, 4096);    // K

  transpose_v<<<dim3(32, 64), tb, 0, stream>>>(QKV + 5120, Vt_g);

  flash_attn<<<dim3(16, 32), 256, 0, stream>>>(QKV, Vt_g, attn);

  gemm_bt<<<dim3(32, 16), 256, 0, stream>>>(attn, Wot, d_out, flag, 2048, 4096, 4096);
}